// Round 10
// baseline (170.380 us; speedup 1.0000x reference)
//
#include <hip/hip_runtime.h>
#include <math.h>

#define B_ 8
#define T_ 1024
#define C_ 768
#define H_ 12
#define D_ 64

typedef __bf16 bf16x8 __attribute__((ext_vector_type(8)));
typedef float  f32x4  __attribute__((ext_vector_type(4)));
typedef unsigned short us8 __attribute__((ext_vector_type(8)));
typedef unsigned int   u32x4v __attribute__((ext_vector_type(4)));

typedef __attribute__((address_space(3))) void lds_void;
typedef __attribute__((address_space(1))) const void glb_void;

#define KSC 0.18033688011112043f   // 0.125 * log2(e)

__device__ __forceinline__ unsigned short f2bf(float f) {
    unsigned int u = __float_as_uint(f);
    u += 0x7fffu + ((u >> 16) & 1u);
    return (unsigned short)(u >> 16);
}

// ---------------- prep: weight transposes (+Q scale) + bias + x->bf16 -------
__global__ __launch_bounds__(256)
void prep_w(const float* __restrict__ x,
            const float* __restrict__ w_qkv, const float* __restrict__ b_qkv,
            const float* __restrict__ w_proj,
            unsigned short* __restrict__ wqT, unsigned short* __restrict__ wpT,
            float* __restrict__ bqs, unsigned short* __restrict__ xb) {
    __shared__ unsigned short Ts[64][65];
    const int id  = blockIdx.x;
    const int tid = threadIdx.x;
    if (id >= 577) {                       // x fp32 -> bf16, coalesced f4->us4
        const int xid = id - 577;
        const float4* xi = (const float4*)x;
        ushort4* xo = (ushort4*)xb;
#pragma unroll
        for (int it = 0; it < 6; it++) {
            const int idx = (xid * 6 + it) * 256 + tid;
            float4 v = xi[idx];
            ushort4 o;
            o.x = f2bf(v.x); o.y = f2bf(v.y); o.z = f2bf(v.z); o.w = f2bf(v.w);
            xo[idx] = o;
        }
        return;
    }
    if (id == 576) {                       // bias with Q-scale
        for (int i = tid; i < 3 * C_; i += 256)
            bqs[i] = b_qkv[i] * (i < C_ ? KSC : 1.f);
        return;
    }
    const float* W; unsigned short* Wt; int N, nlim, t2;
    if (id < 432) { t2 = id;       W = w_qkv;  Wt = wqT; N = 3 * C_; nlim = C_; }
    else          { t2 = id - 432; W = w_proj; Wt = wpT; N = C_;     nlim = 0;  }
    const int ntiles = N / 64;
    const int n0 = (t2 % ntiles) * 64, k0 = (t2 / ntiles) * 64;
    for (int i = tid; i < 4096; i += 256) {
        int n = i & 63, k = i >> 6;
        float sc = (n0 + n < nlim) ? KSC : 1.f;
        Ts[n][k] = f2bf(W[(size_t)(k0 + k) * N + n0 + n] * sc);
    }
    __syncthreads();
    for (int i = tid; i < 4096; i += 256) {
        int k = i & 63, n = i >> 6;
        Wt[(size_t)(n0 + n) * 768 + k0 + k] = Ts[n][k];
    }
}

// ---------------- single-buffered bf16 MFMA GEMM (m97 structure) ------------
// 128x96 tile, BK=64, 256 threads. SINGLE-buffered LDS, natural 28 KB ->
// 5 blocks/CU (LDS floor(160/28.7)=5; VGPR 88 -> 5 waves/SIMD). r9 proved
// the mechanism at 3 blocks/CU (pad-pinned, 167.2 us total): the staging
// drain at each round's first barrier is covered by OTHER co-resident
// blocks, not by in-block double-buffering (r5/r8: both dbuf schedules
// lost at R=12). This round removes the pad -> 5 residents for maximal
// cross-block cover (MfmaUtil was only ~27% at 3/CU: pipes have headroom).
// Tail: 6 blocks/CU of work = 5+1 generations (vs r9's clean 3+3).
// Schedule per round: __syncthreads (drains vmcnt -> staging done) ->
// 24 MFMA -> __syncthreads (reads done) -> stage next round, SAME buffer.
template<int OUT_BF16>
__global__ __launch_bounds__(256, 2)
void gemm_pipe(const unsigned short* __restrict__ A16,
               const unsigned short* __restrict__ Bt, const float* __restrict__ bias,
               void* __restrict__ Cout, int M, int N, int K) {
    __shared__ __align__(16) unsigned short As[8192];   // 128 rows x 8 cells
    __shared__ __align__(16) unsigned short Bs[6144];   // 96 rows x 8 cells

    const int tid  = threadIdx.x;
    const int lane = tid & 63;
    const int c    = lane & 15;
    const int quad = lane >> 4;
    const int wave = tid >> 6;
    const int wm   = (wave >> 1) * 64;     // 2 M-waves
    const int wn   = (wave & 1) * 48;      // 2 N-waves, 48 each
    const int bm   = blockIdx.x * 128;
    const int bn   = blockIdx.y * 96;

    // pre-swizzled global sources: linear LDS cell Lp receives logical cell
    // (row = Lp>>3, kc = (Lp ^ row) & 7)
    const unsigned short* aS[4];
    const unsigned short* bS[3];
#pragma unroll
    for (int p = 0; p < 4; p++) {
        const int Lp = p * 256 + tid;
        const int L  = Lp ^ ((Lp >> 3) & 7);
        aS[p] = A16 + (size_t)(bm + (L >> 3)) * K + (L & 7) * 8;
    }
#pragma unroll
    for (int p = 0; p < 3; p++) {          // 96 rows x 8 cells = 768 = 3*256
        const int Lp = p * 256 + tid;
        const int L  = Lp ^ ((Lp >> 3) & 7);
        bS[p] = Bt + (size_t)(bn + (L >> 3)) * K + (L & 7) * 8;
    }
    const int wb = (tid & 0xC0) * 8;       // wave-uniform LDS base (shorts)

    int aoff[4][2], boff[3][2];
#pragma unroll
    for (int ks = 0; ks < 2; ks++) {
        const int kcA = (ks * 4 + quad) ^ (c & 7);
#pragma unroll
        for (int i = 0; i < 4; i++)
            aoff[i][ks] = ((wm + i * 16 + c) * 8 + kcA) * 8;
#pragma unroll
        for (int j = 0; j < 3; j++)
            boff[j][ks] = ((wn + j * 16 + c) * 8 + kcA) * 8;
    }

    f32x4 acc[4][3];
#pragma unroll
    for (int i = 0; i < 4; i++)
#pragma unroll
        for (int j = 0; j < 3; j++) acc[i][j] = (f32x4){0.f, 0.f, 0.f, 0.f};

    // prologue: stage round 0
#pragma unroll
    for (int p = 0; p < 4; p++) {
        __builtin_amdgcn_global_load_lds((glb_void*)aS[p],
            (lds_void*)(&As[0] + p * 2048 + wb), 16, 0, 0);
        aS[p] += 64;
    }
#pragma unroll
    for (int p = 0; p < 3; p++) {
        __builtin_amdgcn_global_load_lds((glb_void*)bS[p],
            (lds_void*)(&Bs[0] + p * 2048 + wb), 16, 0, 0);
        bS[p] += 64;
    }

    const int R = K >> 6;
    for (int r = 0; r < R; r++) {
        __syncthreads();                   // staging complete (vmcnt drain)

#pragma unroll
        for (int ks = 0; ks < 2; ks++) {
            bf16x8 af[4], bfr[3];
#pragma unroll
            for (int i = 0; i < 4; i++)
                af[i] = __builtin_bit_cast(bf16x8, *(const us8*)&As[aoff[i][ks]]);
#pragma unroll
            for (int j = 0; j < 3; j++)
                bfr[j] = __builtin_bit_cast(bf16x8, *(const us8*)&Bs[boff[j][ks]]);
#pragma unroll
            for (int i = 0; i < 4; i++)
#pragma unroll
                for (int j = 0; j < 3; j++)
                    acc[i][j] = __builtin_amdgcn_mfma_f32_16x16x32_bf16(af[i], bfr[j], acc[i][j], 0, 0, 0);
        }

        __syncthreads();                   // all reads done; buffer free

        if (r + 1 < R) {                   // stage round r+1 into SAME buffer
#pragma unroll
            for (int p = 0; p < 4; p++) {
                __builtin_amdgcn_global_load_lds((glb_void*)aS[p],
                    (lds_void*)(&As[0] + p * 2048 + wb), 16, 0, 0);
                aS[p] += 64;
            }
#pragma unroll
            for (int p = 0; p < 3; p++) {
                __builtin_amdgcn_global_load_lds((glb_void*)bS[p],
                    (lds_void*)(&Bs[0] + p * 2048 + wb), 16, 0, 0);
                bS[p] += 64;
            }
        }
    }

    float bs[3];
#pragma unroll
    for (int j = 0; j < 3; j++) bs[j] = bias[bn + wn + j * 16 + c];
#pragma unroll
    for (int i = 0; i < 4; i++) {
        const int gm = bm + wm + i * 16 + quad * 4;
#pragma unroll
        for (int r = 0; r < 4; r++) {
            const size_t ro = (size_t)(gm + r) * N;
#pragma unroll
            for (int j = 0; j < 3; j++) {
                const float v = acc[i][j][r] + bs[j];
                const int gn = bn + wn + j * 16 + c;
                if (OUT_BF16) ((unsigned short*)Cout)[ro + gn] = f2bf(v);
                else          ((float*)Cout)[ro + gn] = v;
            }
        }
    }
}

// key k -> permuted LDS row, chosen so S^T output lands in PV A-frag layout
__device__ __forceinline__ int sigmaK(int k) {
    return 16 * (2 * (k >> 5) + ((k >> 2) & 1)) + 4 * ((k >> 3) & 3) + (k & 3);
}

// ---------------- flash attention: S^T trick, in-register P -----------------
__global__ __launch_bounds__(256, 3)
void attn_mfma(const unsigned short* __restrict__ qkv, unsigned short* __restrict__ y) {
    __shared__ __align__(16) unsigned short Ks[64 * 72];
    __shared__ __align__(16) unsigned int   Vt[64 * 36];

    const int tid  = threadIdx.x;
    const int wave = tid >> 6;
    const int lane = tid & 63;
    const int c    = lane & 15;
    const int quad = lane >> 4;

    const int id = blockIdx.x;
    const int p  = (id >> 3) & 7;
    const int bh = (id >> 6) * 8 + (id & 7);
    const int b  = bh / H_;
    const int h  = bh - b * H_;

    const int qts[2] = {p, 15 - p};
    const int q0s[2] = {p * 64, (15 - p) * 64};

    const int RS = 3 * C_;
    const unsigned short* kbase = qkv + (size_t)b * T_ * RS + C_ + h * D_;
    const unsigned short* vbase = qkv + (size_t)b * T_ * RS + 2 * C_ + h * D_;

    const u32x4v onesu = {0x3F803F80u, 0x3F803F80u, 0x3F803F80u, 0x3F803F80u};
    const bf16x8 onesf = __builtin_bit_cast(bf16x8, onesu);

    bf16x8 qf[2][2];
#pragma unroll
    for (int t = 0; t < 2; t++) {
        const unsigned short* qrow =
            qkv + ((size_t)(b * T_ + q0s[t] + wave * 16 + c)) * RS + h * D_ + quad * 8;
        qf[t][0] = __builtin_bit_cast(bf16x8, *(const us8*)qrow);
        qf[t][1] = __builtin_bit_cast(bf16x8, *(const us8*)(qrow + 32));
    }

    const int kr0 = tid >> 3, kc0 = tid & 7;
    const int sK0 = sigmaK(kr0) * 72 + kc0 * 8;
    const int sK1 = sigmaK(kr0 + 32) * 72 + kc0 * 8;
    const int dg  = tid >> 4, kp0 = tid & 15;

    us8 kA, kB;
    ushort4 vA0, vB0, vA1, vB1;
    {
        kA = *(const us8*)(kbase + (size_t)kr0 * RS + kc0 * 8);
        kB = *(const us8*)(kbase + (size_t)(kr0 + 32) * RS + kc0 * 8);
        const unsigned short* p0 = vbase + (size_t)(2 * kp0) * RS + dg * 4;
        vA0 = *(const ushort4*)p0;  vB0 = *(const ushort4*)(p0 + RS);
        const unsigned short* p1 = vbase + (size_t)(2 * (kp0 + 16)) * RS + dg * 4;
        vA1 = *(const ushort4*)p1;  vB1 = *(const ushort4*)(p1 + RS);
    }

    f32x4 Oa[2][4];
    f32x4 Ol[2];
#pragma unroll
    for (int t = 0; t < 2; t++) {
        Ol[t] = (f32x4){0.f, 0.f, 0.f, 0.f};
#pragma unroll
        for (int d = 0; d < 4; d++) Oa[t][d] = (f32x4){0.f, 0.f, 0.f, 0.f};
    }

    const int ktEnd = qts[1];
    for (int kt = 0; kt <= ktEnd; kt++) {
        __syncthreads();
        *(us8*)&Ks[sK0] = kA;
        *(us8*)&Ks[sK1] = kB;
        {
            unsigned int* v0 = &Vt[(dg * 4) * 36 + kp0];
            v0[0]   = vA0.x | ((unsigned)vB0.x << 16);
            v0[36]  = vA0.y | ((unsigned)vB0.y << 16);
            v0[72]  = vA0.z | ((unsigned)vB0.z << 16);
            v0[108] = vA0.w | ((unsigned)vB0.w << 16);
            unsigned int* v1 = v0 + 16;
            v1[0]   = vA1.x | ((unsigned)vB1.x << 16);
            v1[36]  = vA1.y | ((unsigned)vB1.y << 16);
            v1[72]  = vA1.z | ((unsigned)vB1.z << 16);
            v1[108] = vA1.w | ((unsigned)vB1.w << 16);
        }
        __syncthreads();

        if (kt < ktEnd) {
            const unsigned short* kp = kbase + (size_t)((kt + 1) * 64) * RS;
            kA = *(const us8*)(kp + (size_t)kr0 * RS + kc0 * 8);
            kB = *(const us8*)(kp + (size_t)(kr0 + 32) * RS + kc0 * 8);
            const unsigned short* vp = vbase + (size_t)((kt + 1) * 64) * RS;
            const unsigned short* p0 = vp + (size_t)(2 * kp0) * RS + dg * 4;
            vA0 = *(const ushort4*)p0;  vB0 = *(const ushort4*)(p0 + RS);
            const unsigned short* p1 = vp + (size_t)(2 * (kp0 + 16)) * RS + dg * 4;
            vA1 = *(const ushort4*)p1;  vB1 = *(const ushort4*)(p1 + RS);
        }

        bf16x8 kf[4][2];
#pragma unroll
        for (int nb = 0; nb < 4; nb++) {
#pragma unroll
            for (int ks = 0; ks < 2; ks++)
                kf[nb][ks] = __builtin_bit_cast(bf16x8,
                    *(const us8*)&Ks[(nb * 16 + c) * 72 + quad * 8 + ks * 32]);
        }

#pragma unroll
        for (int t = 0; t < 2; t++) {
            if (kt > qts[t]) continue;
            const bool diag = (kt == qts[t]);
            const bool doHi = !diag || (wave >= 2);
            const int nbmax = diag ? ((wave >= 2) ? 3 : 1) : 3;

            f32x4 sv[4];
            __builtin_amdgcn_s_setprio(1);
#pragma unroll
            for (int nb = 0; nb < 4; nb++) {
                if (nb <= nbmax) {
                    f32x4 z = (f32x4){0.f, 0.f, 0.f, 0.f};
                    z = __builtin_amdgcn_mfma_f32_16x16x32_bf16(kf[nb][0], qf[t][0], z, 0, 0, 0);
                    sv[nb] = __builtin_amdgcn_mfma_f32_16x16x32_bf16(kf[nb][1], qf[t][1], z, 0, 0, 0);
                }
            }
            __builtin_amdgcn_s_setprio(0);
            if (diag) {
                const int qloc = wave * 16 + c;
#pragma unroll
                for (int nb = 0; nb < 4; nb++) {
                    if (nb <= nbmax) {
                        const int kb = 32 * (nb >> 1) + 4 * (nb & 1) + 8 * quad;
#pragma unroll
                        for (int r = 0; r < 4; r++)
                            if (kb + r > qloc) sv[nb][r] = -INFINITY;
                    }
                }
            }

            unsigned int pd[4][2];
#pragma unroll
            for (int nb = 0; nb < 4; nb++) {
                if (nb <= nbmax) {
                    float p0 = __builtin_amdgcn_exp2f(sv[nb][0]);
                    float p1 = __builtin_amdgcn_exp2f(sv[nb][1]);
                    float p2 = __builtin_amdgcn_exp2f(sv[nb][2]);
                    float p3 = __builtin_amdgcn_exp2f(sv[nb][3]);
                    unsigned u0 = __float_as_uint(p0) + 0x8000u;
                    unsigned u1 = __float_as_uint(p1) + 0x8000u;
                    unsigned u2 = __float_as_uint(p2) + 0x8000u;
                    unsigned u3 = __float_as_uint(p3) + 0x8000u;
                    pd[nb][0] = (u0 >> 16) | (u1 & 0xffff0000u);
                    pd[nb][1] = (u2 >> 16) | (u3 & 0xffff0000u);
                } else {
                    pd[nb][0] = 0u; pd[nb][1] = 0u;
                }
            }

            bf16x8 ap0 = __builtin_bit_cast(bf16x8,
                (u32x4v){pd[0][0], pd[0][1], pd[1][0], pd[1][1]});
            bf16x8 ap1 = __builtin_bit_cast(bf16x8,
                (u32x4v){pd[2][0], pd[2][1], pd[3][0], pd[3][1]});

            __builtin_amdgcn_s_setprio(1);
            Ol[t] = __builtin_amdgcn_mfma_f32_16x16x32_bf16(ap0, onesf, Ol[t], 0, 0, 0);
            if (doHi)
                Ol[t] = __builtin_amdgcn_mfma_f32_16x16x32_bf16(ap1, onesf, Ol[t], 0, 0, 0);

#pragma unroll
            for (int dd = 0; dd < 4; dd++) {
                const unsigned int* vrow = &Vt[(dd * 16 + c) * 36 + quad * 4];
                bf16x8 vb0 = __builtin_bit_cast(bf16x8, *(const u32x4v*)vrow);
                Oa[t][dd] = __builtin_amdgcn_mfma_f32_16x16x32_bf16(ap0, vb0, Oa[t][dd], 0, 0, 0);
                if (doHi) {
                    bf16x8 vb1 = __builtin_bit_cast(bf16x8, *(const u32x4v*)(vrow + 16));
                    Oa[t][dd] = __builtin_amdgcn_mfma_f32_16x16x32_bf16(ap1, vb1, Oa[t][dd], 0, 0, 0);
                }
            }
            __builtin_amdgcn_s_setprio(0);
        }
    }

#pragma unroll
    for (int t = 0; t < 2; t++) {
        unsigned short* yrow =
            y + ((size_t)(b * T_ + q0s[t] + wave * 16)) * C_ + h * D_;
#pragma unroll
        for (int r = 0; r < 4; r++) {
            float inv = 1.f / Ol[t][r];
#pragma unroll
            for (int dd = 0; dd < 4; dd++)
                yrow[(size_t)(quad * 4 + r) * C_ + dd * 16 + c] = f2bf(Oa[t][dd][r] * inv);
        }
    }
}

extern "C" void kernel_launch(void* const* d_in, const int* in_sizes, int n_in,
                              void* d_out, int out_size, void* d_ws, size_t ws_size,
                              hipStream_t stream) {
    const float* x      = (const float*)d_in[0];
    const float* w_qkv  = (const float*)d_in[1];
    const float* b_qkv  = (const float*)d_in[2];
    const float* w_proj = (const float*)d_in[3];
    const float* b_proj = (const float*)d_in[4];
    float* out = (float*)d_out;

    unsigned short* wqT  = (unsigned short*)d_ws;                 // [2304][768]
    unsigned short* wpT  = wqT  + (size_t)3 * C_ * C_;            // [768][768]
    unsigned short* qkvb = wpT  + (size_t)C_ * C_;                // [8192][2304]
    unsigned short* yb   = qkvb + (size_t)B_ * T_ * 3 * C_;       // [8192][768]
    float*          bqs  = (float*)(yb + (size_t)B_ * T_ * C_);   // [2304]

    // yb doubles as xb (bf16 x): consumed by QKV GEMM before attn writes y.
    unsigned short* xb = yb;

    prep_w<<<1601, 256, 0, stream>>>(x, w_qkv, b_qkv, w_proj, wqT, wpT, bqs, xb);

    // qkv = x @ w_qkv + b_qkv  (single-buffered, 5 blk/CU natural LDS)
    gemm_pipe<1><<<dim3(B_ * T_ / 128, 3 * C_ / 96), 256, 0, stream>>>(
        xb, wqT, bqs, qkvb, B_ * T_, 3 * C_, C_);

    // flash attention -> y (bf16), overwrites xb
    attn_mfma<<<8 * B_ * H_, 256, 0, stream>>>(qkvb, yb);

    // out = y @ w_proj + b_proj (single-buffered; 512 blocks)
    gemm_pipe<0><<<dim3(B_ * T_ / 128, C_ / 96), 256, 0, stream>>>(
        yb, wpT, b_proj, out, B_ * T_, C_, C_);
}

// Round 11
// 166.355 us; speedup vs baseline: 1.0242x; 1.0242x over previous
//
#include <hip/hip_runtime.h>
#include <math.h>

#define B_ 8
#define T_ 1024
#define C_ 768
#define H_ 12
#define D_ 64

typedef __bf16 bf16x8 __attribute__((ext_vector_type(8)));
typedef float  f32x4  __attribute__((ext_vector_type(4)));
typedef unsigned short us8 __attribute__((ext_vector_type(8)));
typedef unsigned int   u32x4v __attribute__((ext_vector_type(4)));

typedef __attribute__((address_space(3))) void lds_void;
typedef __attribute__((address_space(1))) const void glb_void;

#define KSC 0.18033688011112043f   // 0.125 * log2(e)

__device__ __forceinline__ unsigned short f2bf(float f) {
    unsigned int u = __float_as_uint(f);
    u += 0x7fffu + ((u >> 16) & 1u);
    return (unsigned short)(u >> 16);
}

// ---------------- prep: weight transposes (+Q scale) + bias + x->bf16 -------
__global__ __launch_bounds__(256)
void prep_w(const float* __restrict__ x,
            const float* __restrict__ w_qkv, const float* __restrict__ b_qkv,
            const float* __restrict__ w_proj,
            unsigned short* __restrict__ wqT, unsigned short* __restrict__ wpT,
            float* __restrict__ bqs, unsigned short* __restrict__ xb) {
    __shared__ unsigned short Ts[64][65];
    const int id  = blockIdx.x;
    const int tid = threadIdx.x;
    if (id >= 577) {                       // x fp32 -> bf16, coalesced f4->us4
        const int xid = id - 577;
        const float4* xi = (const float4*)x;
        ushort4* xo = (ushort4*)xb;
#pragma unroll
        for (int it = 0; it < 6; it++) {
            const int idx = (xid * 6 + it) * 256 + tid;
            float4 v = xi[idx];
            ushort4 o;
            o.x = f2bf(v.x); o.y = f2bf(v.y); o.z = f2bf(v.z); o.w = f2bf(v.w);
            xo[idx] = o;
        }
        return;
    }
    if (id == 576) {                       // bias with Q-scale
        for (int i = tid; i < 3 * C_; i += 256)
            bqs[i] = b_qkv[i] * (i < C_ ? KSC : 1.f);
        return;
    }
    const float* W; unsigned short* Wt; int N, nlim, t2;
    if (id < 432) { t2 = id;       W = w_qkv;  Wt = wqT; N = 3 * C_; nlim = C_; }
    else          { t2 = id - 432; W = w_proj; Wt = wpT; N = C_;     nlim = 0;  }
    const int ntiles = N / 64;
    const int n0 = (t2 % ntiles) * 64, k0 = (t2 / ntiles) * 64;
    for (int i = tid; i < 4096; i += 256) {
        int n = i & 63, k = i >> 6;
        float sc = (n0 + n < nlim) ? KSC : 1.f;
        Ts[n][k] = f2bf(W[(size_t)(k0 + k) * N + n0 + n] * sc);
    }
    __syncthreads();
    for (int i = tid; i < 4096; i += 256) {
        int k = i & 63, n = i >> 6;
        Wt[(size_t)(n0 + n) * 768 + k0 + k] = Ts[n][k];
    }
}

// -------- 256x96 single-buffered bf16 MFMA GEMM (QKV): C = A·Bt^T + b -------
// BM=256, BN=96, BK=64, 256 threads (4 waves: 2M x 2N, per-wave 128x48,
// acc[8][3]). Single-buffered LDS = 44 KB NATURAL -> 3 blocks/CU (r9's
// proven mechanism: staging drains covered by co-resident blocks; r10
// showed 5/CU over-shares, 3/CU is the sweet spot). Doubled per-round
// amortization: 48 MFMA/wave per barrier-pair (vs 24 at BM=128).
// Grid 32x24 = 768 = EXACTLY 3 x 256 CU -> single generation, zero tail
// (r9 had 2 generations). Register discipline: ks-phase split into two
// af[4] halves (peak ~130 VGPR); __launch_bounds__(256,3) caps at 170.
// Source stride identity: linear cell Lp+256 -> L+256 (swizzle XOR only
// touches low 3 bits), so one base pointer + p*32*K covers all 8 A loads.
// Same verified cell swizzle as always: logical (row,kc) at linear
// (row, kc^(row&7)); pre-swizzled global source, linear LDS dest.
template<int OUT_BF16>
__global__ __launch_bounds__(256, 3)
void gemm_big(const unsigned short* __restrict__ A16,
              const unsigned short* __restrict__ Bt, const float* __restrict__ bias,
              void* __restrict__ Cout, int M, int N, int K) {
    __shared__ __align__(16) unsigned short As[16384];  // 256 rows x 8 cells
    __shared__ __align__(16) unsigned short Bs[6144];   // 96 rows x 8 cells

    const int tid  = threadIdx.x;
    const int lane = tid & 63;
    const int c    = lane & 15;
    const int quad = lane >> 4;
    const int wave = tid >> 6;
    const int wm   = (wave >> 1) * 128;    // 2 M-waves, 128 rows each
    const int wn   = (wave & 1) * 48;      // 2 N-waves, 48 each
    const int bm   = blockIdx.x * 256;
    const int bn   = blockIdx.y * 96;

    // single base per operand; p-th load at base + p*32*K (see header note)
    const unsigned short* aS0;
    const unsigned short* bS0;
    {
        const int Lp = tid;
        const int L  = Lp ^ ((Lp >> 3) & 7);
        aS0 = A16 + (size_t)(bm + (L >> 3)) * K + (L & 7) * 8;
        bS0 = Bt  + (size_t)(bn + (L >> 3)) * K + (L & 7) * 8;
    }
    const int wb = (tid & 0xC0) * 8;       // wave-uniform LDS base (shorts)

    int aoff[8][2], boff[3][2];
#pragma unroll
    for (int ks = 0; ks < 2; ks++) {
        const int kcA = (ks * 4 + quad) ^ (c & 7);
#pragma unroll
        for (int i = 0; i < 8; i++)
            aoff[i][ks] = ((wm + i * 16 + c) * 8 + kcA) * 8;
#pragma unroll
        for (int j = 0; j < 3; j++)
            boff[j][ks] = ((wn + j * 16 + c) * 8 + kcA) * 8;
    }

    f32x4 acc[8][3];
#pragma unroll
    for (int i = 0; i < 8; i++)
#pragma unroll
        for (int j = 0; j < 3; j++) acc[i][j] = (f32x4){0.f, 0.f, 0.f, 0.f};

#define STAGE_BIG()                                                            \
    {                                                                          \
        _Pragma("unroll")                                                      \
        for (int p = 0; p < 8; p++)                                            \
            __builtin_amdgcn_global_load_lds((glb_void*)(aS0 + (size_t)p * 32 * K), \
                (lds_void*)(&As[0] + p * 2048 + wb), 16, 0, 0);                \
        aS0 += 64;                                                             \
        _Pragma("unroll")                                                      \
        for (int p = 0; p < 3; p++)                                            \
            __builtin_amdgcn_global_load_lds((glb_void*)(bS0 + (size_t)p * 32 * K), \
                (lds_void*)(&Bs[0] + p * 2048 + wb), 16, 0, 0);                \
        bS0 += 64;                                                             \
    }

    STAGE_BIG()                            // prologue: round 0

    const int R = K >> 6;
    for (int r = 0; r < R; r++) {
        __syncthreads();                   // staging complete (vmcnt drain)

#pragma unroll
        for (int ks = 0; ks < 2; ks++) {
            bf16x8 bfr[3];
#pragma unroll
            for (int j = 0; j < 3; j++)
                bfr[j] = __builtin_bit_cast(bf16x8, *(const us8*)&Bs[boff[j][ks]]);
#pragma unroll
            for (int half = 0; half < 2; half++) {
                bf16x8 af[4];
#pragma unroll
                for (int i = 0; i < 4; i++)
                    af[i] = __builtin_bit_cast(bf16x8,
                        *(const us8*)&As[aoff[half * 4 + i][ks]]);
#pragma unroll
                for (int i = 0; i < 4; i++)
#pragma unroll
                    for (int j = 0; j < 3; j++)
                        acc[half * 4 + i][j] = __builtin_amdgcn_mfma_f32_16x16x32_bf16(
                            af[i], bfr[j], acc[half * 4 + i][j], 0, 0, 0);
            }
        }

        __syncthreads();                   // all reads done; buffer free

        if (r + 1 < R) STAGE_BIG()         // stage round r+1, SAME buffer
    }
#undef STAGE_BIG

    float bs[3];
#pragma unroll
    for (int j = 0; j < 3; j++) bs[j] = bias[bn + wn + j * 16 + c];
#pragma unroll
    for (int i = 0; i < 8; i++) {
        const int gm = bm + wm + i * 16 + quad * 4;
#pragma unroll
        for (int r = 0; r < 4; r++) {
            const size_t ro = (size_t)(gm + r) * N;
#pragma unroll
            for (int j = 0; j < 3; j++) {
                const float v = acc[i][j][r] + bs[j];
                const int gn = bn + wn + j * 16 + c;
                if (OUT_BF16) ((unsigned short*)Cout)[ro + gn] = f2bf(v);
                else          ((float*)Cout)[ro + gn] = v;
            }
        }
    }
}

// ---------------- single-buffered bf16 MFMA GEMM (proj, r10 version) --------
// 128x96, 256 threads, single-buffered 28 KB. Proj runs 512 blocks -> 2/CU
// actual occupancy regardless of cap; r9/r10 measured identical for proj.
template<int OUT_BF16>
__global__ __launch_bounds__(256, 2)
void gemm_pipe(const unsigned short* __restrict__ A16,
               const unsigned short* __restrict__ Bt, const float* __restrict__ bias,
               void* __restrict__ Cout, int M, int N, int K) {
    __shared__ __align__(16) unsigned short As[8192];
    __shared__ __align__(16) unsigned short Bs[6144];

    const int tid  = threadIdx.x;
    const int lane = tid & 63;
    const int c    = lane & 15;
    const int quad = lane >> 4;
    const int wave = tid >> 6;
    const int wm   = (wave >> 1) * 64;
    const int wn   = (wave & 1) * 48;
    const int bm   = blockIdx.x * 128;
    const int bn   = blockIdx.y * 96;

    const unsigned short* aS[4];
    const unsigned short* bS[3];
#pragma unroll
    for (int p = 0; p < 4; p++) {
        const int Lp = p * 256 + tid;
        const int L  = Lp ^ ((Lp >> 3) & 7);
        aS[p] = A16 + (size_t)(bm + (L >> 3)) * K + (L & 7) * 8;
    }
#pragma unroll
    for (int p = 0; p < 3; p++) {
        const int Lp = p * 256 + tid;
        const int L  = Lp ^ ((Lp >> 3) & 7);
        bS[p] = Bt + (size_t)(bn + (L >> 3)) * K + (L & 7) * 8;
    }
    const int wb = (tid & 0xC0) * 8;

    int aoff[4][2], boff[3][2];
#pragma unroll
    for (int ks = 0; ks < 2; ks++) {
        const int kcA = (ks * 4 + quad) ^ (c & 7);
#pragma unroll
        for (int i = 0; i < 4; i++)
            aoff[i][ks] = ((wm + i * 16 + c) * 8 + kcA) * 8;
#pragma unroll
        for (int j = 0; j < 3; j++)
            boff[j][ks] = ((wn + j * 16 + c) * 8 + kcA) * 8;
    }

    f32x4 acc[4][3];
#pragma unroll
    for (int i = 0; i < 4; i++)
#pragma unroll
        for (int j = 0; j < 3; j++) acc[i][j] = (f32x4){0.f, 0.f, 0.f, 0.f};

#pragma unroll
    for (int p = 0; p < 4; p++) {
        __builtin_amdgcn_global_load_lds((glb_void*)aS[p],
            (lds_void*)(&As[0] + p * 2048 + wb), 16, 0, 0);
        aS[p] += 64;
    }
#pragma unroll
    for (int p = 0; p < 3; p++) {
        __builtin_amdgcn_global_load_lds((glb_void*)bS[p],
            (lds_void*)(&Bs[0] + p * 2048 + wb), 16, 0, 0);
        bS[p] += 64;
    }

    const int R = K >> 6;
    for (int r = 0; r < R; r++) {
        __syncthreads();

#pragma unroll
        for (int ks = 0; ks < 2; ks++) {
            bf16x8 af[4], bfr[3];
#pragma unroll
            for (int i = 0; i < 4; i++)
                af[i] = __builtin_bit_cast(bf16x8, *(const us8*)&As[aoff[i][ks]]);
#pragma unroll
            for (int j = 0; j < 3; j++)
                bfr[j] = __builtin_bit_cast(bf16x8, *(const us8*)&Bs[boff[j][ks]]);
#pragma unroll
            for (int i = 0; i < 4; i++)
#pragma unroll
                for (int j = 0; j < 3; j++)
                    acc[i][j] = __builtin_amdgcn_mfma_f32_16x16x32_bf16(af[i], bfr[j], acc[i][j], 0, 0, 0);
        }

        __syncthreads();

        if (r + 1 < R) {
#pragma unroll
            for (int p = 0; p < 4; p++) {
                __builtin_amdgcn_global_load_lds((glb_void*)aS[p],
                    (lds_void*)(&As[0] + p * 2048 + wb), 16, 0, 0);
                aS[p] += 64;
            }
#pragma unroll
            for (int p = 0; p < 3; p++) {
                __builtin_amdgcn_global_load_lds((glb_void*)bS[p],
                    (lds_void*)(&Bs[0] + p * 2048 + wb), 16, 0, 0);
                bS[p] += 64;
            }
        }
    }

    float bs[3];
#pragma unroll
    for (int j = 0; j < 3; j++) bs[j] = bias[bn + wn + j * 16 + c];
#pragma unroll
    for (int i = 0; i < 4; i++) {
        const int gm = bm + wm + i * 16 + quad * 4;
#pragma unroll
        for (int r = 0; r < 4; r++) {
            const size_t ro = (size_t)(gm + r) * N;
#pragma unroll
            for (int j = 0; j < 3; j++) {
                const float v = acc[i][j][r] + bs[j];
                const int gn = bn + wn + j * 16 + c;
                if (OUT_BF16) ((unsigned short*)Cout)[ro + gn] = f2bf(v);
                else          ((float*)Cout)[ro + gn] = v;
            }
        }
    }
}

// key k -> permuted LDS row, chosen so S^T output lands in PV A-frag layout
__device__ __forceinline__ int sigmaK(int k) {
    return 16 * (2 * (k >> 5) + ((k >> 2) & 1)) + 4 * ((k >> 3) & 3) + (k & 3);
}

// ---------------- flash attention: S^T trick, in-register P -----------------
__global__ __launch_bounds__(256, 3)
void attn_mfma(const unsigned short* __restrict__ qkv, unsigned short* __restrict__ y) {
    __shared__ __align__(16) unsigned short Ks[64 * 72];
    __shared__ __align__(16) unsigned int   Vt[64 * 36];

    const int tid  = threadIdx.x;
    const int wave = tid >> 6;
    const int lane = tid & 63;
    const int c    = lane & 15;
    const int quad = lane >> 4;

    const int id = blockIdx.x;
    const int p  = (id >> 3) & 7;
    const int bh = (id >> 6) * 8 + (id & 7);
    const int b  = bh / H_;
    const int h  = bh - b * H_;

    const int qts[2] = {p, 15 - p};
    const int q0s[2] = {p * 64, (15 - p) * 64};

    const int RS = 3 * C_;
    const unsigned short* kbase = qkv + (size_t)b * T_ * RS + C_ + h * D_;
    const unsigned short* vbase = qkv + (size_t)b * T_ * RS + 2 * C_ + h * D_;

    const u32x4v onesu = {0x3F803F80u, 0x3F803F80u, 0x3F803F80u, 0x3F803F80u};
    const bf16x8 onesf = __builtin_bit_cast(bf16x8, onesu);

    bf16x8 qf[2][2];
#pragma unroll
    for (int t = 0; t < 2; t++) {
        const unsigned short* qrow =
            qkv + ((size_t)(b * T_ + q0s[t] + wave * 16 + c)) * RS + h * D_ + quad * 8;
        qf[t][0] = __builtin_bit_cast(bf16x8, *(const us8*)qrow);
        qf[t][1] = __builtin_bit_cast(bf16x8, *(const us8*)(qrow + 32));
    }

    const int kr0 = tid >> 3, kc0 = tid & 7;
    const int sK0 = sigmaK(kr0) * 72 + kc0 * 8;
    const int sK1 = sigmaK(kr0 + 32) * 72 + kc0 * 8;
    const int dg  = tid >> 4, kp0 = tid & 15;

    us8 kA, kB;
    ushort4 vA0, vB0, vA1, vB1;
    {
        kA = *(const us8*)(kbase + (size_t)kr0 * RS + kc0 * 8);
        kB = *(const us8*)(kbase + (size_t)(kr0 + 32) * RS + kc0 * 8);
        const unsigned short* p0 = vbase + (size_t)(2 * kp0) * RS + dg * 4;
        vA0 = *(const ushort4*)p0;  vB0 = *(const ushort4*)(p0 + RS);
        const unsigned short* p1 = vbase + (size_t)(2 * (kp0 + 16)) * RS + dg * 4;
        vA1 = *(const ushort4*)p1;  vB1 = *(const ushort4*)(p1 + RS);
    }

    f32x4 Oa[2][4];
    f32x4 Ol[2];
#pragma unroll
    for (int t = 0; t < 2; t++) {
        Ol[t] = (f32x4){0.f, 0.f, 0.f, 0.f};
#pragma unroll
        for (int d = 0; d < 4; d++) Oa[t][d] = (f32x4){0.f, 0.f, 0.f, 0.f};
    }

    const int ktEnd = qts[1];
    for (int kt = 0; kt <= ktEnd; kt++) {
        __syncthreads();
        *(us8*)&Ks[sK0] = kA;
        *(us8*)&Ks[sK1] = kB;
        {
            unsigned int* v0 = &Vt[(dg * 4) * 36 + kp0];
            v0[0]   = vA0.x | ((unsigned)vB0.x << 16);
            v0[36]  = vA0.y | ((unsigned)vB0.y << 16);
            v0[72]  = vA0.z | ((unsigned)vB0.z << 16);
            v0[108] = vA0.w | ((unsigned)vB0.w << 16);
            unsigned int* v1 = v0 + 16;
            v1[0]   = vA1.x | ((unsigned)vB1.x << 16);
            v1[36]  = vA1.y | ((unsigned)vB1.y << 16);
            v1[72]  = vA1.z | ((unsigned)vB1.z << 16);
            v1[108] = vA1.w | ((unsigned)vB1.w << 16);
        }
        __syncthreads();

        if (kt < ktEnd) {
            const unsigned short* kp = kbase + (size_t)((kt + 1) * 64) * RS;
            kA = *(const us8*)(kp + (size_t)kr0 * RS + kc0 * 8);
            kB = *(const us8*)(kp + (size_t)(kr0 + 32) * RS + kc0 * 8);
            const unsigned short* vp = vbase + (size_t)((kt + 1) * 64) * RS;
            const unsigned short* p0 = vp + (size_t)(2 * kp0) * RS + dg * 4;
            vA0 = *(const ushort4*)p0;  vB0 = *(const ushort4*)(p0 + RS);
            const unsigned short* p1 = vp + (size_t)(2 * (kp0 + 16)) * RS + dg * 4;
            vA1 = *(const ushort4*)p1;  vB1 = *(const ushort4*)(p1 + RS);
        }

        bf16x8 kf[4][2];
#pragma unroll
        for (int nb = 0; nb < 4; nb++) {
#pragma unroll
            for (int ks = 0; ks < 2; ks++)
                kf[nb][ks] = __builtin_bit_cast(bf16x8,
                    *(const us8*)&Ks[(nb * 16 + c) * 72 + quad * 8 + ks * 32]);
        }

#pragma unroll
        for (int t = 0; t < 2; t++) {
            if (kt > qts[t]) continue;
            const bool diag = (kt == qts[t]);
            const bool doHi = !diag || (wave >= 2);
            const int nbmax = diag ? ((wave >= 2) ? 3 : 1) : 3;

            f32x4 sv[4];
            __builtin_amdgcn_s_setprio(1);
#pragma unroll
            for (int nb = 0; nb < 4; nb++) {
                if (nb <= nbmax) {
                    f32x4 z = (f32x4){0.f, 0.f, 0.f, 0.f};
                    z = __builtin_amdgcn_mfma_f32_16x16x32_bf16(kf[nb][0], qf[t][0], z, 0, 0, 0);
                    sv[nb] = __builtin_amdgcn_mfma_f32_16x16x32_bf16(kf[nb][1], qf[t][1], z, 0, 0, 0);
                }
            }
            __builtin_amdgcn_s_setprio(0);
            if (diag) {
                const int qloc = wave * 16 + c;
#pragma unroll
                for (int nb = 0; nb < 4; nb++) {
                    if (nb <= nbmax) {
                        const int kb = 32 * (nb >> 1) + 4 * (nb & 1) + 8 * quad;
#pragma unroll
                        for (int r = 0; r < 4; r++)
                            if (kb + r > qloc) sv[nb][r] = -INFINITY;
                    }
                }
            }

            unsigned int pd[4][2];
#pragma unroll
            for (int nb = 0; nb < 4; nb++) {
                if (nb <= nbmax) {
                    float p0 = __builtin_amdgcn_exp2f(sv[nb][0]);
                    float p1 = __builtin_amdgcn_exp2f(sv[nb][1]);
                    float p2 = __builtin_amdgcn_exp2f(sv[nb][2]);
                    float p3 = __builtin_amdgcn_exp2f(sv[nb][3]);
                    unsigned u0 = __float_as_uint(p0) + 0x8000u;
                    unsigned u1 = __float_as_uint(p1) + 0x8000u;
                    unsigned u2 = __float_as_uint(p2) + 0x8000u;
                    unsigned u3 = __float_as_uint(p3) + 0x8000u;
                    pd[nb][0] = (u0 >> 16) | (u1 & 0xffff0000u);
                    pd[nb][1] = (u2 >> 16) | (u3 & 0xffff0000u);
                } else {
                    pd[nb][0] = 0u; pd[nb][1] = 0u;
                }
            }

            bf16x8 ap0 = __builtin_bit_cast(bf16x8,
                (u32x4v){pd[0][0], pd[0][1], pd[1][0], pd[1][1]});
            bf16x8 ap1 = __builtin_bit_cast(bf16x8,
                (u32x4v){pd[2][0], pd[2][1], pd[3][0], pd[3][1]});

            __builtin_amdgcn_s_setprio(1);
            Ol[t] = __builtin_amdgcn_mfma_f32_16x16x32_bf16(ap0, onesf, Ol[t], 0, 0, 0);
            if (doHi)
                Ol[t] = __builtin_amdgcn_mfma_f32_16x16x32_bf16(ap1, onesf, Ol[t], 0, 0, 0);

#pragma unroll
            for (int dd = 0; dd < 4; dd++) {
                const unsigned int* vrow = &Vt[(dd * 16 + c) * 36 + quad * 4];
                bf16x8 vb0 = __builtin_bit_cast(bf16x8, *(const u32x4v*)vrow);
                Oa[t][dd] = __builtin_amdgcn_mfma_f32_16x16x32_bf16(ap0, vb0, Oa[t][dd], 0, 0, 0);
                if (doHi) {
                    bf16x8 vb1 = __builtin_bit_cast(bf16x8, *(const u32x4v*)(vrow + 16));
                    Oa[t][dd] = __builtin_amdgcn_mfma_f32_16x16x32_bf16(ap1, vb1, Oa[t][dd], 0, 0, 0);
                }
            }
            __builtin_amdgcn_s_setprio(0);
        }
    }

#pragma unroll
    for (int t = 0; t < 2; t++) {
        unsigned short* yrow =
            y + ((size_t)(b * T_ + q0s[t] + wave * 16)) * C_ + h * D_;
#pragma unroll
        for (int r = 0; r < 4; r++) {
            float inv = 1.f / Ol[t][r];
#pragma unroll
            for (int dd = 0; dd < 4; dd++)
                yrow[(size_t)(quad * 4 + r) * C_ + dd * 16 + c] = f2bf(Oa[t][dd][r] * inv);
        }
    }
}

extern "C" void kernel_launch(void* const* d_in, const int* in_sizes, int n_in,
                              void* d_out, int out_size, void* d_ws, size_t ws_size,
                              hipStream_t stream) {
    const float* x      = (const float*)d_in[0];
    const float* w_qkv  = (const float*)d_in[1];
    const float* b_qkv  = (const float*)d_in[2];
    const float* w_proj = (const float*)d_in[3];
    const float* b_proj = (const float*)d_in[4];
    float* out = (float*)d_out;

    unsigned short* wqT  = (unsigned short*)d_ws;                 // [2304][768]
    unsigned short* wpT  = wqT  + (size_t)3 * C_ * C_;            // [768][768]
    unsigned short* qkvb = wpT  + (size_t)C_ * C_;                // [8192][2304]
    unsigned short* yb   = qkvb + (size_t)B_ * T_ * 3 * C_;       // [8192][768]
    float*          bqs  = (float*)(yb + (size_t)B_ * T_ * C_);   // [2304]

    // yb doubles as xb (bf16 x): consumed by QKV GEMM before attn writes y.
    unsigned short* xb = yb;

    prep_w<<<1601, 256, 0, stream>>>(x, w_qkv, b_qkv, w_proj, wqT, wpT, bqs, xb);

    // qkv = x @ w_qkv + b_qkv  (256x96, 3 blk/CU, 768 blocks = 1 generation)
    gemm_big<1><<<dim3(B_ * T_ / 256, 3 * C_ / 96), 256, 0, stream>>>(
        xb, wqT, bqs, qkvb, B_ * T_, 3 * C_, C_);

    // flash attention -> y (bf16), overwrites xb
    attn_mfma<<<8 * B_ * H_, 256, 0, stream>>>(qkvb, yb);

    // out = y @ w_proj + b_proj (128x96; 512 blocks, 2/CU, one generation)
    gemm_pipe<0><<<dim3(B_ * T_ / 128, C_ / 96), 256, 0, stream>>>(
        yb, wpT, b_proj, out, B_ * T_, C_, C_);
}